// Round 10
// baseline (287.028 us; speedup 1.0000x reference)
//
#include <hip/hip_runtime.h>

#define T_STEPS 60
#define HID 128
#define ROWS 16
#define NBLK (16384 / ROWS)  // 1024 blocks

typedef __attribute__((ext_vector_type(8))) short short8;
typedef __attribute__((ext_vector_type(4))) float f32x4;

#define K1 1.44269504088896340736f  // log2(e)

__device__ __forceinline__ unsigned short f2bf(float f) {
  unsigned u = __float_as_uint(f);
  return (unsigned short)((u + 0x7fffu + ((u >> 16) & 1u)) >> 16);
}
__device__ __forceinline__ float sigm(float x) {
  return __builtin_amdgcn_rcpf(1.0f + __expf(-x));
}

// LDS map (bytes):
//   [0,4096):      h buffer 0 (16 rows x 128 units bf16, row r at r*256, swizzled)
//   [4096,8192):   h buffer 1
//   [8192,12032):  out staging: [16 rows][60 t] f32
#define HB0 0
#define HB1 4096
#define OUT_BASE 8192
#define LDS_BYTES 12032

__global__ __launch_bounds__(512, 3) void lstm_fused(
    const float* __restrict__ x, const float* __restrict__ W_enc,
    const float* __restrict__ b_enc, const float* __restrict__ W_ih,
    const float* __restrict__ W_hh, const float* __restrict__ b_ih,
    const float* __restrict__ b_hh, const float* __restrict__ W_dec,
    const float* __restrict__ b_dec, float* __restrict__ out) {
  __shared__ __align__(16) unsigned char lds[LDS_BYTES];

  const int tid = threadIdx.x;
  const int wav = tid >> 6;
  const int lane = tid & 63;
  const int l15 = lane & 15;
  const int l4 = lane >> 4;
  const int u = wav * 16 + l15;        // hidden unit owned by this lane
  const int row0 = blockIdx.x * ROWS;  // global batch row base
  float* outf = (float*)(lds + OUT_BASE);

  // zero h buf0 (4096 B)
  for (int i = tid; i < 1024; i += 512) ((unsigned*)(lds + HB0))[i] = 0u;

  // ---- xp = enc @ W_ih^T + b_ih + b_hh, f32 IN REGISTERS, acc layout ----
  // (f16/LDS xp was the R3/R5 failure; must stay f32.)
  f32x4 xp4[4];
  {
    float xr0[4], xr1[4], xr2[4];
#pragma unroll
    for (int v = 0; v < 4; ++v) {
      int r = 4 * l4 + v;  // C-fragment row for this lane
      const float* xp_ = x + (size_t)(row0 + r) * 3;
      xr0[v] = xp_[0];
      xr1[v] = xp_[1];
      xr2[v] = xp_[2];
    }
#pragma unroll
    for (int gt = 0; gt < 4; ++gt) {
      float bias = b_ih[gt * 128 + u] + b_hh[gt * 128 + u];
#pragma unroll
      for (int v = 0; v < 4; ++v) xp4[gt][v] = bias;
    }
    const f32x4* wr0 = (const f32x4*)(W_ih + (size_t)u * 64);
    const f32x4* wr1 = (const f32x4*)(W_ih + (size_t)(128 + u) * 64);
    const f32x4* wr2 = (const f32x4*)(W_ih + (size_t)(256 + u) * 64);
    const f32x4* wr3 = (const f32x4*)(W_ih + (size_t)(384 + u) * 64);
    for (int e4 = 0; e4 < 16; ++e4) {
      f32x4 w0 = wr0[e4], w1 = wr1[e4], w2 = wr2[e4], w3 = wr3[e4];
#pragma unroll
      for (int j = 0; j < 4; ++j) {
        int e = e4 * 4 + j;
        float we0 = W_enc[e * 3], we1 = W_enc[e * 3 + 1], we2 = W_enc[e * 3 + 2];
        float be = b_enc[e];
#pragma unroll
        for (int v = 0; v < 4; ++v) {
          float ev = fmaf(we0, xr0[v], fmaf(we1, xr1[v], fmaf(we2, xr2[v], be)));
          xp4[0][v] = fmaf(w0[j], ev, xp4[0][v]);
          xp4[1][v] = fmaf(w1[j], ev, xp4[1][v]);
          xp4[2][v] = fmaf(w2[j], ev, xp4[2][v]);
          xp4[3][v] = fmaf(w3[j], ev, xp4[3][v]);
        }
      }
    }
    // prescale into exp2 domain: y = -log2e * preact (i,f,o), -2log2e (g)
#pragma unroll
    for (int gt = 0; gt < 4; ++gt) {
      float s = (gt == 2) ? (-2.0f * K1) : (-K1);
#pragma unroll
      for (int v = 0; v < 4; ++v) xp4[gt][v] *= s;
    }
  }

  // ---- W_hh bf16 B-fragments, prescaled into exp2 domain (R1-verified layout) ----
  short8 bw[4][4];
#pragma unroll
  for (int gt = 0; gt < 4; ++gt) {
    float s = (gt == 2) ? (-2.0f * K1) : (-K1);
#pragma unroll
    for (int kt = 0; kt < 4; ++kt) {
      const float* p = W_hh + (size_t)(gt * 128 + u) * HID + kt * 32 + 8 * l4;
      short8 f;
#pragma unroll
      for (int j = 0; j < 8; ++j) f[j] = (short)f2bf(s * p[j]);
      bw[gt][kt] = f;
    }
  }

  // ---- decode B-tile: col 0 = W_dec (only l15==0 lanes hold nonzero frag) ----
  short8 dw[4];
#pragma unroll
  for (int kt = 0; kt < 4; ++kt) {
    short8 f = {};
    if (l15 == 0) {
      const float* p = W_dec + kt * 32 + 8 * l4;
#pragma unroll
      for (int j = 0; j < 8; ++j) f[j] = (short)f2bf(p[j]);
    }
    dw[kt] = f;
  }

  // c held in scaled domain: ct = -2log2e * c  (so e^{-2c} = 2^ct)
  float ct[4];
#pragma unroll
  for (int v = 0; v < 4; ++v) ct[v] = 0.0f;

  // ---- precomputed LDS addresses (swizzle bits 4-6, consistent on rd/wr) ----
  const unsigned swzA =
      (((unsigned)(l15 & 7)) << 4) ^ (((unsigned)(l15 & 8)) << 2);
  unsigned rdA[4];
#pragma unroll
  for (int kt = 0; kt < 4; ++kt)
    rdA[kt] = ((unsigned)(l15 * 256 + l4 * 16 + kt * 64)) ^ swzA;
  unsigned wrA[4];
#pragma unroll
  for (int v = 0; v < 4; ++v) {
    unsigned rr = (unsigned)(4 * l4 + v);
    wrA[v] = (rr * 256 + (unsigned)u * 2) ^ ((rr & 7u) << 4) ^ ((rr & 8u) << 2);
  }
  const float kneg = -2.0f * K1;
  const float kpos = 2.0f * K1;

  __syncthreads();

  // gate math in exp2 domain (R7-verified):
  //   e^{-i}=2^acc0, e^{-f}=2^acc1, e^{-2g}=2^acc2, e^{-o}=2^acc3
  //   ct' = [ct*A*G + k(1-eg)*F]/(F*A*G), k=-2log2e;  h=(1-ec)/(Bo*(1+ec))
#define STEP(RB, WB, icur)                                                     \
  {                                                                            \
    short8 af[4];                                                              \
    _Pragma("unroll") for (int kt = 0; kt < 4; ++kt) af[kt] =                  \
        *(const short8*)(lds + (RB) + rdA[kt]);                                \
    f32x4 acc[4];                                                              \
    _Pragma("unroll") for (int gt = 0; gt < 4; ++gt) {                         \
      acc[gt] = __builtin_amdgcn_mfma_f32_16x16x32_bf16(af[0], bw[gt][0],      \
                                                        xp4[gt], 0, 0, 0);     \
      _Pragma("unroll") for (int kt = 1; kt < 4; ++kt) acc[gt] =               \
          __builtin_amdgcn_mfma_f32_16x16x32_bf16(af[kt], bw[gt][kt],          \
                                                  acc[gt], 0, 0, 0);           \
    }                                                                          \
    f32x4 ad = {};                                                             \
    _Pragma("unroll") for (int kt = 0; kt < 4; ++kt) ad =                      \
        __builtin_amdgcn_mfma_f32_16x16x32_bf16(af[kt], dw[kt], ad, 0, 0, 0);  \
    _Pragma("unroll") for (int v = 0; v < 4; ++v) {                            \
      float ea = __builtin_amdgcn_exp2f(acc[0][v]);                            \
      float ef = __builtin_amdgcn_exp2f(acc[1][v]);                            \
      float eg = __builtin_amdgcn_exp2f(acc[2][v]);                            \
      float eo = __builtin_amdgcn_exp2f(acc[3][v]);                            \
      float A = 1.0f + ea, F = 1.0f + ef, G = 1.0f + eg, Bo = 1.0f + eo;       \
      float AG = A * G;                                                        \
      float r = __builtin_amdgcn_rcpf(F * AG);                                 \
      float tt = fmaf(kpos, eg, kneg);                                         \
      float num = fmaf(ct[v], AG, tt * F);                                     \
      float cn = num * r;                                                      \
      ct[v] = cn;                                                              \
      float ec = __builtin_amdgcn_exp2f(cn);                                   \
      float r2 = __builtin_amdgcn_rcpf(Bo * (1.0f + ec));                      \
      float h = (1.0f - ec) * r2;                                              \
      *(unsigned short*)(lds + (WB) + wrA[v]) = f2bf(h);                       \
    }                                                                          \
    if (wav == 0 && l15 == 0 && (icur) > 0) {                                  \
      _Pragma("unroll") for (int v = 0; v < 4; ++v)                            \
          outf[(4 * l4 + v) * T_STEPS + (icur)-1] = ad[v];                     \
    }                                                                          \
    __syncthreads();                                                           \
  }

  for (int i = 0; i < T_STEPS; i += 2) {
    STEP(HB0, HB1, i)
    STEP(HB1, HB0, i + 1)
  }
#undef STEP

  // ---- drain: y for h_60 (in HB0) -> column 59 ----
  if (wav == 0) {
    short8 af[4];
#pragma unroll
    for (int kt = 0; kt < 4; ++kt)
      af[kt] = *(const short8*)(lds + HB0 + rdA[kt]);
    f32x4 ad = {};
#pragma unroll
    for (int kt = 0; kt < 4; ++kt)
      ad = __builtin_amdgcn_mfma_f32_16x16x32_bf16(af[kt], dw[kt], ad, 0, 0, 0);
    if (l15 == 0) {
#pragma unroll
      for (int v = 0; v < 4; ++v)
        outf[(4 * l4 + v) * T_STEPS + (T_STEPS - 1)] = ad[v];
    }
  }
  __syncthreads();

  // ---- epilogue: sigmoid + coalesced store (16 rows x 15 float4 chunks) ----
  const float bdec = b_dec[0];
  if (tid < 240) {
    int r = tid / 15, c4 = tid - r * 15;
    f32x4 s = *(const f32x4*)&outf[r * T_STEPS + c4 * 4];
    f32x4 o;
#pragma unroll
    for (int k = 0; k < 4; ++k) o[k] = sigm(s[k] + bdec);
    *(f32x4*)(out + (size_t)(row0 + r) * T_STEPS + c4 * 4) = o;
  }
}

extern "C" void kernel_launch(void* const* d_in, const int* in_sizes, int n_in,
                              void* d_out, int out_size, void* d_ws, size_t ws_size,
                              hipStream_t stream) {
  const float* x = (const float*)d_in[0];
  const float* W_enc = (const float*)d_in[1];
  const float* b_enc = (const float*)d_in[2];
  const float* W_ih = (const float*)d_in[3];
  const float* W_hh = (const float*)d_in[4];
  const float* b_ih = (const float*)d_in[5];
  const float* b_hh = (const float*)d_in[6];
  const float* W_dec = (const float*)d_in[7];
  const float* b_dec = (const float*)d_in[8];
  float* out = (float*)d_out;

  dim3 grid(NBLK);  // 1024 blocks x 16 rows
  dim3 block(512);
  lstm_fused<<<grid, block, 0, stream>>>(x, W_enc, b_enc, W_ih, W_hh, b_ih, b_hh,
                                         W_dec, b_dec, out);
}

// Round 11
// 251.814 us; speedup vs baseline: 1.1398x; 1.1398x over previous
//
#include <hip/hip_runtime.h>

#define T_STEPS 60
#define HID 128
#define ROWS 16
#define NBLK (16384 / ROWS)  // 1024 blocks

typedef __attribute__((ext_vector_type(8))) short short8;
typedef __attribute__((ext_vector_type(4))) float f32x4;

#define K1 1.44269504088896340736f  // log2(e)

__device__ __forceinline__ unsigned short f2bf(float f) {
  unsigned u = __float_as_uint(f);
  return (unsigned short)((u + 0x7fffu + ((u >> 16) & 1u)) >> 16);
}
__device__ __forceinline__ float sigm(float x) {
  return __builtin_amdgcn_rcpf(1.0f + __expf(-x));
}
// butterfly-add over the 16-lane DPP row (sums l15 dimension, preserves l4)
template <int CTRL>
__device__ __forceinline__ float dppadd(float x) {
  int y = __builtin_amdgcn_update_dpp(0, __builtin_bit_cast(int, x), CTRL, 0xf,
                                      0xf, false);
  return x + __builtin_bit_cast(float, y);
}

// LDS map (bytes):
//   [0,4096):      h buffer 0 (16 rows x 128 units bf16, row r at r*256, swizzled)
//   [4096,8192):   h buffer 1
//   [8192,39168):  decode partials f32: [8 waves][60 t][16 rows], wave stride 968 f32
#define HB0 0
#define HB1 4096
#define PART 8192
#define WSTRIDE 968  // 60*16 + 8 pad (de-banks the 8 waves' b128 writes)
#define LDS_BYTES (PART + 8 * WSTRIDE * 4)

__global__ __launch_bounds__(512, 4) void lstm_fused(
    const float* __restrict__ x, const float* __restrict__ W_enc,
    const float* __restrict__ b_enc, const float* __restrict__ W_ih,
    const float* __restrict__ W_hh, const float* __restrict__ b_ih,
    const float* __restrict__ b_hh, const float* __restrict__ W_dec,
    const float* __restrict__ b_dec, float* __restrict__ out) {
  __shared__ __align__(16) unsigned char lds[LDS_BYTES];

  const int tid = threadIdx.x;
  const int wav = tid >> 6;
  const int lane = tid & 63;
  const int l15 = lane & 15;
  const int l4 = lane >> 4;
  const int u = wav * 16 + l15;        // hidden unit owned by this lane
  const int row0 = blockIdx.x * ROWS;  // global batch row base

  // zero h buf0 (4096 B)
  for (int i = tid; i < 1024; i += 512) ((unsigned*)(lds + HB0))[i] = 0u;

  // ---- xp = enc @ W_ih^T + b_ih + b_hh, f32 IN REGISTERS, acc layout ----
  // (f16/LDS xp was the R3/R5 failure; must stay f32.)
  f32x4 xp4[4];
  {
    float xr0[4], xr1[4], xr2[4];
#pragma unroll
    for (int v = 0; v < 4; ++v) {
      int r = 4 * l4 + v;  // C-fragment row for this lane
      const float* xp_ = x + (size_t)(row0 + r) * 3;
      xr0[v] = xp_[0];
      xr1[v] = xp_[1];
      xr2[v] = xp_[2];
    }
#pragma unroll
    for (int gt = 0; gt < 4; ++gt) {
      float bias = b_ih[gt * 128 + u] + b_hh[gt * 128 + u];
#pragma unroll
      for (int v = 0; v < 4; ++v) xp4[gt][v] = bias;
    }
    const f32x4* wr0 = (const f32x4*)(W_ih + (size_t)u * 64);
    const f32x4* wr1 = (const f32x4*)(W_ih + (size_t)(128 + u) * 64);
    const f32x4* wr2 = (const f32x4*)(W_ih + (size_t)(256 + u) * 64);
    const f32x4* wr3 = (const f32x4*)(W_ih + (size_t)(384 + u) * 64);
    for (int e4 = 0; e4 < 16; ++e4) {
      f32x4 w0 = wr0[e4], w1 = wr1[e4], w2 = wr2[e4], w3 = wr3[e4];
#pragma unroll
      for (int j = 0; j < 4; ++j) {
        int e = e4 * 4 + j;
        float we0 = W_enc[e * 3], we1 = W_enc[e * 3 + 1], we2 = W_enc[e * 3 + 2];
        float be = b_enc[e];
#pragma unroll
        for (int v = 0; v < 4; ++v) {
          float ev = fmaf(we0, xr0[v], fmaf(we1, xr1[v], fmaf(we2, xr2[v], be)));
          xp4[0][v] = fmaf(w0[j], ev, xp4[0][v]);
          xp4[1][v] = fmaf(w1[j], ev, xp4[1][v]);
          xp4[2][v] = fmaf(w2[j], ev, xp4[2][v]);
          xp4[3][v] = fmaf(w3[j], ev, xp4[3][v]);
        }
      }
    }
    // prescale into exp2 domain: y = -log2e * preact (i,f,o), -2log2e (g)
#pragma unroll
    for (int gt = 0; gt < 4; ++gt) {
      float s = (gt == 2) ? (-2.0f * K1) : (-K1);
#pragma unroll
      for (int v = 0; v < 4; ++v) xp4[gt][v] *= s;
    }
  }

  // ---- W_hh bf16 B-fragments, prescaled into exp2 domain (R1-verified layout) ----
  short8 bw[4][4];
#pragma unroll
  for (int gt = 0; gt < 4; ++gt) {
    float s = (gt == 2) ? (-2.0f * K1) : (-K1);
#pragma unroll
    for (int kt = 0; kt < 4; ++kt) {
      const float* p = W_hh + (size_t)(gt * 128 + u) * HID + kt * 32 + 8 * l4;
      short8 f;
#pragma unroll
      for (int j = 0; j < 8; ++j) f[j] = (short)f2bf(s * p[j]);
      bw[gt][kt] = f;
    }
  }

  // c held in scaled domain: ct = -2log2e * c  (so e^{-2c} = 2^ct)
  float ct[4];
#pragma unroll
  for (int v = 0; v < 4; ++v) ct[v] = 0.0f;

  // ---- precomputed LDS addresses (swizzle bits 4-6, consistent on rd/wr) ----
  const unsigned swzA =
      (((unsigned)(l15 & 7)) << 4) ^ (((unsigned)(l15 & 8)) << 2);
  unsigned rdA[4];
#pragma unroll
  for (int kt = 0; kt < 4; ++kt)
    rdA[kt] = ((unsigned)(l15 * 256 + l4 * 16 + kt * 64)) ^ swzA;
  unsigned wrA[4];
#pragma unroll
  for (int v = 0; v < 4; ++v) {
    unsigned rr = (unsigned)(4 * l4 + v);
    wrA[v] = (rr * 256 + (unsigned)u * 2) ^ ((rr & 7u) << 4) ^ ((rr & 8u) << 2);
  }
  const float wdu = W_dec[u];  // decode weight for this lane's unit
  const unsigned ptByte = (unsigned)(wav * WSTRIDE + 4 * l4) * 4;
  const float kneg = -2.0f * K1;
  const float kpos = 2.0f * K1;

  __syncthreads();

  // gate math in exp2 domain (R7-verified):
  //   e^{-i}=2^acc0, e^{-f}=2^acc1, e^{-2g}=2^acc2, e^{-o}=2^acc3
  //   ct' = [ct*A*G + k(1-eg)*F]/(F*A*G), k=-2log2e;  h=(1-ec)/(Bo*(1+ec))
#define STEP(RB, WB, tcur)                                                     \
  {                                                                            \
    f32x4 acc[4];                                                              \
    {                                                                          \
      short8 af = *(const short8*)(lds + (RB) + rdA[0]);                       \
      _Pragma("unroll") for (int gt = 0; gt < 4; ++gt) acc[gt] =               \
          __builtin_amdgcn_mfma_f32_16x16x32_bf16(af, bw[gt][0], xp4[gt],      \
                                                  0, 0, 0);                    \
    }                                                                          \
    _Pragma("unroll") for (int kt = 1; kt < 4; ++kt) {                         \
      short8 af = *(const short8*)(lds + (RB) + rdA[kt]);                      \
      _Pragma("unroll") for (int gt = 0; gt < 4; ++gt) acc[gt] =               \
          __builtin_amdgcn_mfma_f32_16x16x32_bf16(af, bw[gt][kt], acc[gt],     \
                                                  0, 0, 0);                    \
    }                                                                          \
    f32x4 pz;                                                                  \
    _Pragma("unroll") for (int v = 0; v < 4; ++v) {                            \
      float ea = __builtin_amdgcn_exp2f(acc[0][v]);                            \
      float ef = __builtin_amdgcn_exp2f(acc[1][v]);                            \
      float eg = __builtin_amdgcn_exp2f(acc[2][v]);                            \
      float eo = __builtin_amdgcn_exp2f(acc[3][v]);                            \
      float A = 1.0f + ea, F = 1.0f + ef, G = 1.0f + eg, Bo = 1.0f + eo;       \
      float AG = A * G;                                                        \
      float r = __builtin_amdgcn_rcpf(F * AG);                                 \
      float tt = fmaf(kpos, eg, kneg);                                         \
      float num = fmaf(ct[v], AG, tt * F);                                     \
      float cn = num * r;                                                      \
      ct[v] = cn;                                                              \
      float ec = __builtin_amdgcn_exp2f(cn);                                   \
      float r2 = __builtin_amdgcn_rcpf(Bo * (1.0f + ec));                      \
      float h = (1.0f - ec) * r2;                                              \
      *(unsigned short*)(lds + (WB) + wrA[v]) = f2bf(h);                       \
      pz[v] = h * wdu;                                                         \
    }                                                                          \
    /* in-register 16-lane (l15) butterfly via DPP; l4 rows preserved */       \
    _Pragma("unroll") for (int v = 0; v < 4; ++v) pz[v] =                      \
        dppadd<0x140>(dppadd<0x141>(dppadd<0x4E>(dppadd<0xB1>(pz[v]))));       \
    if (l15 == 0)                                                              \
      *(f32x4*)(lds + PART + ptByte + (unsigned)(tcur)*64) = pz;               \
    __syncthreads();                                                           \
  }

  for (int t = 0; t < T_STEPS; t += 2) {
    STEP(HB0, HB1, t)
    STEP(HB1, HB0, t + 1)
  }
#undef STEP

  // ---- epilogue: cross-wave sum of partials + sigmoid + coalesced store ----
  const float bdec = b_dec[0];
  const float* partf = (const float*)(lds + PART);
  for (int i = tid; i < 16 * T_STEPS; i += 512) {
    int r = i / T_STEPS, t = i - r * T_STEPS;
    float s = 0.0f;
#pragma unroll
    for (int w = 0; w < 8; ++w) s += partf[w * WSTRIDE + t * 16 + r];
    out[(size_t)(row0 + r) * T_STEPS + t] = sigm(s + bdec);
  }
}

extern "C" void kernel_launch(void* const* d_in, const int* in_sizes, int n_in,
                              void* d_out, int out_size, void* d_ws, size_t ws_size,
                              hipStream_t stream) {
  const float* x = (const float*)d_in[0];
  const float* W_enc = (const float*)d_in[1];
  const float* b_enc = (const float*)d_in[2];
  const float* W_ih = (const float*)d_in[3];
  const float* W_hh = (const float*)d_in[4];
  const float* b_ih = (const float*)d_in[5];
  const float* b_hh = (const float*)d_in[6];
  const float* W_dec = (const float*)d_in[7];
  const float* b_dec = (const float*)d_in[8];
  float* out = (float*)d_out;

  dim3 grid(NBLK);  // 1024 blocks x 16 rows
  dim3 block(512);
  lstm_fused<<<grid, block, 0, stream>>>(x, W_enc, b_enc, W_ih, W_hh, b_ih, b_hh,
                                         W_dec, b_dec, out);
}